// Round 2
// baseline (27878.174 us; speedup 1.0000x reference)
//
#include <hip/hip_runtime.h>
#include <math.h>

typedef unsigned int u32;

#define T_    600
#define FIN_  120

// ---- ws byte offsets ----
#define OFF_BAR      0ull          // (unused this round, kept for layout stability)
#define OFF_HENC     2048ull       // [2 parity][2 dir][512][32] f32 = 262144
#define OFF_CENC     264192ull     // [2 dir][512][32] = 131072
#define OFF_HD       395264ull     // [2 parity][32][512] = 131072
#define OFF_CD       526336ull     // [32][512] = 65536
#define STATE_BYTES  591872ull     // memset-0 region
#define OFF_LAST     591872ull     // [32][512]
#define OFF_Q        657408ull     // [32][512]
#define OFF_CTX      722944ull     // [32][1024]
#define OFF_SCORES   854016ull     // [32][600]
#define OFF_STATS    930816ull     // [32][2]
#define OFF_AUDIOT   931840ull     // [600][120][32] = 9216000
#define OFF_ENC2     10147840ull   // [32][1024][600] = 78643200
#define OFF_KEYT     88791040ull   // [32][512][600] = 39321600
#define OFF_VAL      128112640ull  // [32][600][1024] = 78643200

__device__ __forceinline__ float sigf(float x) { return 1.0f / (1.0f + expf(-x)); }

// ---------------- prep ----------------
__global__ __launch_bounds__(256) void k_prep_audio(const float* __restrict__ audio,
                                                    float* __restrict__ audio_T) {
  int idx = blockIdx.x * 256 + threadIdx.x;
  if (idx >= T_ * FIN_ * 32) return;
  int b = idx & 31;
  int r = idx >> 5;
  int f = r % FIN_;
  int t = r / FIN_;
  audio_T[idx] = audio[(size_t)b * (T_ * FIN_) + t * FIN_ + f];
}

__global__ __launch_bounds__(256) void k_init_last(const float* __restrict__ E,
                                                   float* __restrict__ last) {
  int idx = blockIdx.x * 256 + threadIdx.x;
  if (idx < 32 * 512) last[idx] = E[idx & 511];
}

// ---------------- encoder: one time-step per launch (grid 512 x 256) ----------------
struct EncP {
  const float* audio_T;
  const float* Wih_f; const float* Whh_f; const float* b_f;
  const float* Wih_b; const float* Whh_b; const float* b_b;
  float* h_enc; float* c_enc; float* enc2;
};

__global__ __launch_bounds__(256) void k_enc_step(EncP P, int s) {
  __shared__ float Wl[8192];   // 16 rows x 512 (Whh slice for this block's 4 j)
  __shared__ float hl[8192];   // [512 j][16 b] XOR-swizzled
  const int tid = threadIdx.x, bid = blockIdx.x;
  const int grp = bid >> 7;            // 0..3 : (dir, bhalf)
  const int dir = grp >> 1, bhalf = grp & 1;
  const int jblk = bid & 127;
  const int b_lo = tid & 15, quad = (tid >> 4) & 3, j_lo = tid >> 6;
  const int j = jblk * 4 + j_lo;
  const int bG = bhalf * 16 + b_lo;
  const float* Wih  = dir ? P.Wih_b : P.Wih_f;
  const float* Whh  = dir ? P.Whh_b : P.Whh_f;
  const float* bias = dir ? P.b_b   : P.b_f;

  const int t = dir ? (599 - s) : s;
  const int p = s & 1;

  // stage Whh rows
  for (int rr = 0; rr < 16; rr++) {
    int R = ((rr & 3) << 9) + jblk * 4 + (rr >> 2);
    for (int c = tid; c < 512; c += 256) Wl[rr * 512 + c] = Whh[(size_t)R * 512 + c];
  }
  // stage h (previous step's output, parity p)
  {
    const float* hsrc = P.h_enc + (size_t)(p * 2 + dir) * 16384;
    for (int idx = tid; idx < 8192; idx += 256) {
      int jj = idx >> 4, bb = idx & 15;
      hl[jj * 16 + (bb ^ ((jj >> 7) << 2))] = hsrc[jj * 32 + bhalf * 16 + bb];
    }
  }
  __syncthreads();

  const float bia0 = bias[j], bia1 = bias[512 + j], bia2 = bias[1024 + j], bia3 = bias[1536 + j];
  const float* WihR0 = Wih + (size_t)(j       ) * 120;
  const float* WihR1 = Wih + (size_t)(512  + j) * 120;
  const float* WihR2 = Wih + (size_t)(1024 + j) * 120;
  const float* WihR3 = Wih + (size_t)(1536 + j) * 120;
  const float* Wr0 = Wl + (j_lo * 4 + 0) * 512;
  const float* Wr1 = Wl + (j_lo * 4 + 1) * 512;
  const float* Wr2 = Wl + (j_lo * 4 + 2) * 512;
  const float* Wr3 = Wl + (j_lo * 4 + 3) * 512;
  const int bswz = b_lo ^ (quad << 2);
  const int xs = 32 * quad;
  const int xe = (quad == 3) ? 120 : (32 * quad + 32);
  const int hs = 128 * quad;

  float a0 = 0.f, a1 = 0.f, a2 = 0.f, a3 = 0.f;
  {
    const float* xg = P.audio_T + (size_t)t * 3840 + bG;
    for (int k = xs; k < xe; k += 4) {
      float4 w0 = *(const float4*)(WihR0 + k);
      float4 w1 = *(const float4*)(WihR1 + k);
      float4 w2 = *(const float4*)(WihR2 + k);
      float4 w3 = *(const float4*)(WihR3 + k);
      float x0 = xg[(k + 0) * 32], x1 = xg[(k + 1) * 32];
      float x2 = xg[(k + 2) * 32], x3 = xg[(k + 3) * 32];
      a0 += w0.x * x0 + w0.y * x1 + w0.z * x2 + w0.w * x3;
      a1 += w1.x * x0 + w1.y * x1 + w1.z * x2 + w1.w * x3;
      a2 += w2.x * x0 + w2.y * x1 + w2.z * x2 + w2.w * x3;
      a3 += w3.x * x0 + w3.y * x1 + w3.z * x2 + w3.w * x3;
    }
  }
  #pragma unroll 4
  for (int kk = 0; kk < 128; kk += 4) {
    const int k = hs + kk;
    float4 w0 = *(const float4*)(Wr0 + k);
    float4 w1 = *(const float4*)(Wr1 + k);
    float4 w2 = *(const float4*)(Wr2 + k);
    float4 w3 = *(const float4*)(Wr3 + k);
    float x0 = hl[(k + 0) * 16 + bswz], x1 = hl[(k + 1) * 16 + bswz];
    float x2 = hl[(k + 2) * 16 + bswz], x3 = hl[(k + 3) * 16 + bswz];
    a0 += w0.x * x0 + w0.y * x1 + w0.z * x2 + w0.w * x3;
    a1 += w1.x * x0 + w1.y * x1 + w1.z * x2 + w1.w * x3;
    a2 += w2.x * x0 + w2.y * x1 + w2.z * x2 + w2.w * x3;
    a3 += w3.x * x0 + w3.y * x1 + w3.z * x2 + w3.w * x3;
  }
  a0 += __shfl_xor(a0, 16); a0 += __shfl_xor(a0, 32);
  a1 += __shfl_xor(a1, 16); a1 += __shfl_xor(a1, 32);
  a2 += __shfl_xor(a2, 16); a2 += __shfl_xor(a2, 32);
  a3 += __shfl_xor(a3, 16); a3 += __shfl_xor(a3, 32);
  if (quad == 0) {
    float gi = a0 + bia0, gf = a1 + bia1, gg = a2 + bia2, go = a3 + bia3;
    const int ci = dir * 16384 + j * 32 + bG;
    float co = P.c_enc[ci];
    float cn = sigf(gf) * co + sigf(gi) * tanhf(gg);
    float hn = sigf(go) * tanhf(cn);
    P.c_enc[ci] = cn;
    P.h_enc[(size_t)(((p ^ 1) * 2 + dir)) * 16384 + j * 32 + bG] = hn;
    P.enc2[(size_t)bG * 614400 + (size_t)(dir * 512 + j) * 600 + t] = hn;
  }
}

// ---------------- key/val GEMM: [19200 x 1024] @ [1024 x 1536] + tanh ----------------
struct KVP {
  const float* enc2; const float* Wk; const float* bk; const float* Wv; const float* bv;
  float* key_T; float* val;
};

__global__ __launch_bounds__(256) void k_keyval(KVP P) {
  __shared__ float As[16 * 132];
  __shared__ float Bs[16 * 132];
  const int tid = threadIdx.x, bid = blockIdx.x;
  const int mt = bid % 150, nt = bid / 150;
  const int m0 = mt * 128, n0 = nt * 128;
  const int tx = tid & 15, ty = tid >> 4;
  const int mmS = tid & 127;
  const int gmS = m0 + mmS;
  const int bS = gmS / 600, tS = gmS % 600;
  const int kkS0 = tid >> 7;
  const int nnS0 = tid >> 4;
  const int kkSB = tid & 15;
  float acc[8][8];
  #pragma unroll
  for (int i = 0; i < 8; i++)
    #pragma unroll
    for (int jj = 0; jj < 8; jj++) acc[i][jj] = 0.f;
  for (int k0 = 0; k0 < 1024; k0 += 16) {
    #pragma unroll
    for (int r = 0; r < 8; r++) {
      int kk = kkS0 + 2 * r;
      As[kk * 132 + mmS] = P.enc2[(size_t)bS * 614400 + (size_t)(k0 + kk) * 600 + tS];
    }
    #pragma unroll
    for (int r = 0; r < 8; r++) {
      int nn = nnS0 + 16 * r;
      int n = n0 + nn;
      const float* src = (n < 512) ? (P.Wk + (size_t)n * 1024) : (P.Wv + (size_t)(n - 512) * 1024);
      Bs[kkSB * 132 + nn] = src[k0 + kkSB];
    }
    __syncthreads();
    #pragma unroll
    for (int kk = 0; kk < 16; kk++) {
      float4 A0 = *(const float4*)&As[kk * 132 + ty * 8];
      float4 A1 = *(const float4*)&As[kk * 132 + ty * 8 + 4];
      float4 B0 = *(const float4*)&Bs[kk * 132 + tx * 8];
      float4 B1 = *(const float4*)&Bs[kk * 132 + tx * 8 + 4];
      float av[8] = {A0.x, A0.y, A0.z, A0.w, A1.x, A1.y, A1.z, A1.w};
      float bw[8] = {B0.x, B0.y, B0.z, B0.w, B1.x, B1.y, B1.z, B1.w};
      #pragma unroll
      for (int i = 0; i < 8; i++)
        #pragma unroll
        for (int jj = 0; jj < 8; jj++) acc[i][jj] += av[i] * bw[jj];
    }
    __syncthreads();
  }
  #pragma unroll
  for (int i = 0; i < 8; i++) {
    int gm = m0 + ty * 8 + i;
    int b = gm / 600, t = gm % 600;
    #pragma unroll
    for (int jj = 0; jj < 8; jj++) {
      int n = n0 + tx * 8 + jj;
      float bia = (n < 512) ? P.bk[n] : P.bv[n - 512];
      float v = tanhf(acc[i][jj] + bia);
      if (n < 512) P.key_T[(size_t)b * 307200 + (size_t)n * 600 + t] = v;
      else         P.val  [(size_t)b * 614400 + (size_t)t * 1024 + (n - 512)] = v;
    }
  }
}

// ---------------- decoder phase kernels ----------------
struct DecP {
  const float* Wq; const float* bq;
  const float* Wih_d; const float* Whh_d; const float* b_d;
  const float* Wc; const float* bc; const float* E;
  const int* flen;
  const float* key_T; const float* val;
  float* h_d; float* c_d; float* last; float* q; float* ctx;
  float* scores; float* stats;
  float* out;
};

// gates + cell update for step i. reads h[i&1], writes h[(i&1)^1]. grid 256.
__global__ __launch_bounds__(256) void k_dec_gates(DecP P, int i) {
  __shared__ float sm[16384];
  const int tid = threadIdx.x, bid = blockIdx.x;
  const int p = i & 1;
  const int bq4 = bid >> 6;
  const int jblk = bid & 63;
  const int b_lo = tid & 7;
  const int quad = (tid >> 3) & 3;
  const int j_lo = tid >> 5;
  const int bG = bq4 * 8 + b_lo;
  const int j = jblk * 8 + j_lo;
  const float* hsrc = P.h_d + p * 16384;
  for (int idx = tid; idx < 8 * 2048; idx += 256) {
    int bb = idx >> 11, c = idx & 2047;
    int gb = bq4 * 8 + bb;
    float v;
    if (c < 512)       v = P.last[gb * 512 + c];
    else if (c < 1536) v = P.ctx[gb * 1024 + (c - 512)];
    else               v = hsrc[gb * 512 + (c - 1536)];
    sm[bb * 2048 + (c ^ (bb << 2))] = v;
  }
  __syncthreads();
  const int k0 = quad << 9;
  const float* wbp; int rs, ko;
  if (quad < 3) { wbp = P.Wih_d; rs = 1536; ko = k0; }
  else          { wbp = P.Whh_d; rs = 512;  ko = 0;  }
  const float* r0 = wbp + (size_t)(j       ) * rs + ko;
  const float* r1 = wbp + (size_t)(512  + j) * rs + ko;
  const float* r2 = wbp + (size_t)(1024 + j) * rs + ko;
  const float* r3 = wbp + (size_t)(1536 + j) * rs + ko;
  const float* xb = sm + b_lo * 2048 + k0;
  const int xo = b_lo << 2;
  float a0 = 0.f, a1 = 0.f, a2 = 0.f, a3 = 0.f;
  #pragma unroll 4
  for (int k = 0; k < 512; k += 4) {
    float4 w0 = *(const float4*)(r0 + k);
    float4 w1 = *(const float4*)(r1 + k);
    float4 w2 = *(const float4*)(r2 + k);
    float4 w3 = *(const float4*)(r3 + k);
    float4 x  = *(const float4*)(xb + (k ^ xo));
    a0 += w0.x * x.x + w0.y * x.y + w0.z * x.z + w0.w * x.w;
    a1 += w1.x * x.x + w1.y * x.y + w1.z * x.z + w1.w * x.w;
    a2 += w2.x * x.x + w2.y * x.y + w2.z * x.z + w2.w * x.w;
    a3 += w3.x * x.x + w3.y * x.y + w3.z * x.z + w3.w * x.w;
  }
  a0 += __shfl_xor(a0, 8); a0 += __shfl_xor(a0, 16);
  a1 += __shfl_xor(a1, 8); a1 += __shfl_xor(a1, 16);
  a2 += __shfl_xor(a2, 8); a2 += __shfl_xor(a2, 16);
  a3 += __shfl_xor(a3, 8); a3 += __shfl_xor(a3, 16);
  if (quad == 0) {
    float gi = a0 + P.b_d[j];
    float gf = a1 + P.b_d[512 + j];
    float gg = a2 + P.b_d[1024 + j];
    float go = a3 + P.b_d[1536 + j];
    int ci = bG * 512 + j;
    float co = P.c_d[ci];
    float cn = sigf(gf) * co + sigf(gi) * tanhf(gg);
    float hn = sigf(go) * tanhf(cn);
    P.c_d[ci] = cn;
    P.h_d[(p ^ 1) * 16384 + ci] = hn;
  }
}

// logits_i (blocks 0..223) || q_{i+1} (blocks 224..255). i==-1: q only. grid 256.
__global__ __launch_bounds__(256) void k_dec_logits_q(DecP P, int i) {
  __shared__ float sm[16384];
  const int tid = threadIdx.x, bid = blockIdx.x;
  const int pn = (i & 1) ^ 1;
  const float* hsrc = P.h_d + pn * 16384;
  for (int idx = tid; idx < 16384; idx += 256) {
    int bb = idx >> 9, k = idx & 511;
    sm[bb * 512 + (k ^ ((bb & 7) << 2))] = hsrc[idx];
  }
  __syncthreads();
  if (bid < 224) {
    if (i < 0) return;
    for (int pidx = bid * 256 + tid; pidx < 65536; pidx += 57344) {
      int bb = pidx & 31;
      int v0 = (pidx >> 5) << 1;
      const float* w0 = P.Wc + (size_t)v0 * 512;
      const float* w1 = w0 + 512;
      const float* hbp = sm + bb * 512;
      const int xo = (bb & 7) << 2;
      float s0 = 0.f, s1 = 0.f;
      #pragma unroll 4
      for (int k = 0; k < 512; k += 4) {
        float4 A0 = *(const float4*)(w0 + k);
        float4 A1 = *(const float4*)(w1 + k);
        int kx = k ^ xo;
        float h0 = hbp[kx], h1 = hbp[kx + 1], h2 = hbp[kx + 2], h3 = hbp[kx + 3];
        s0 += A0.x * h0 + A0.y * h1 + A0.z * h2 + A0.w * h3;
        s1 += A1.x * h0 + A1.y * h1 + A1.z * h2 + A1.w * h3;
      }
      size_t o = (size_t)bb * 491520 + (size_t)i * 4096 + v0;
      P.out[o]     = s0 + P.bc[v0];
      P.out[o + 1] = s1 + P.bc[v0 + 1];
    }
  } else {
    int pidx = (bid - 224) * 256 + tid;   // 0..8191
    int bb = pidx & 31;
    int d0 = (pidx >> 5) << 1;
    const float* w0 = P.Wq + (size_t)d0 * 512;
    const float* w1 = w0 + 512;
    const float* hbp = sm + bb * 512;
    const int xo = (bb & 7) << 2;
    float s0 = 0.f, s1 = 0.f;
    #pragma unroll 4
    for (int k = 0; k < 512; k += 4) {
      float4 A0 = *(const float4*)(w0 + k);
      float4 A1 = *(const float4*)(w1 + k);
      int kx = k ^ xo;
      float h0 = hbp[kx], h1 = hbp[kx + 1], h2 = hbp[kx + 2], h3 = hbp[kx + 3];
      s0 += A0.x * h0 + A0.y * h1 + A0.z * h2 + A0.w * h3;
      s1 += A1.x * h0 + A1.y * h1 + A1.z * h2 + A1.w * h3;
    }
    P.q[bb * 512 + d0]     = tanhf(s0 + P.bq[d0]);
    P.q[bb * 512 + d0 + 1] = tanhf(s1 + P.bq[d0 + 1]);
  }
}

// argmax_i -> last (blocks 0..31) || scores_{i+1}+softmax stats (blocks 32..63). grid 64.
__global__ __launch_bounds__(256) void k_dec_amax(DecP P, int i, int do_scores) {
  __shared__ float sm[2600];
  const int tid = threadIdx.x, bid = blockIdx.x;
  if (bid < 32) {
    if (i < 0) return;
    const float* row = P.out + (size_t)bid * 491520 + (size_t)i * 4096;
    float bv = -INFINITY; int bi = 0;
    for (int v = tid; v < 4096; v += 256) {
      float x = row[v];
      if (x > bv) { bv = x; bi = v; }
    }
    float* smax = sm;
    int* sidx = (int*)(sm + 256);
    smax[tid] = bv; sidx[tid] = bi;
    __syncthreads();
    for (int off = 128; off > 0; off >>= 1) {
      if (tid < off) {
        float ov = smax[tid + off]; int oi = sidx[tid + off];
        if (ov > smax[tid] || (ov == smax[tid] && oi < sidx[tid])) { smax[tid] = ov; sidx[tid] = oi; }
      }
      __syncthreads();
    }
    int widx = sidx[0];
    for (int k = tid; k < 512; k += 256) P.last[bid * 512 + k] = P.E[(size_t)widx * 512 + k];
  } else {
    if (!do_scores) return;
    int bb = bid - 32;
    float* ql  = sm;            // 512
    float* part = sm + 512;     // 3*600
    float* red = sm + 2340;     // 256
    for (int k = tid; k < 512; k += 256) ql[k] = P.q[bb * 512 + k];
    __syncthreads();
    if (tid < 225) {
      int tg = tid % 75, kq = tid / 75;
      int t0 = tg * 8;
      int kb_ = (kq == 0) ? 0   : ((kq == 1) ? 170 : 340);
      int ke_ = (kq == 0) ? 170 : ((kq == 1) ? 340 : 512);
      const float* kp = P.key_T + (size_t)bb * 307200 + t0;
      float s0=0,s1=0,s2=0,s3=0,s4=0,s5=0,s6=0,s7=0;
      for (int k = kb_; k < ke_; k++) {
        float qv = ql[k];
        const float* kr = kp + (size_t)k * 600;
        float4 u0 = *(const float4*)(kr);
        float4 u1 = *(const float4*)(kr + 4);
        s0 += qv * u0.x; s1 += qv * u0.y; s2 += qv * u0.z; s3 += qv * u0.w;
        s4 += qv * u1.x; s5 += qv * u1.y; s6 += qv * u1.z; s7 += qv * u1.w;
      }
      float* pp = part + kq * 600 + t0;
      pp[0]=s0; pp[1]=s1; pp[2]=s2; pp[3]=s3; pp[4]=s4; pp[5]=s5; pp[6]=s6; pp[7]=s7;
    }
    __syncthreads();
    int len = P.flen[bb];
    float sc0, sc1, sc2;
    {
      int t = tid;
      float s = part[t] + part[600 + t] + part[1200 + t];
      sc0 = (t < len) ? 2.0f * s : -1e30f;
      P.scores[bb * 600 + t] = sc0;
    }
    {
      int t = tid + 256;
      float s = part[t] + part[600 + t] + part[1200 + t];
      sc1 = (t < len) ? 2.0f * s : -1e30f;
      P.scores[bb * 600 + t] = sc1;
    }
    bool has2 = (tid < 88);
    sc2 = -INFINITY;
    if (has2) {
      int t = tid + 512;
      float s = part[t] + part[600 + t] + part[1200 + t];
      sc2 = (t < len) ? 2.0f * s : -1e30f;
      P.scores[bb * 600 + t] = sc2;
    }
    float lm = fmaxf(fmaxf(sc0, sc1), sc2);
    red[tid] = lm;
    __syncthreads();
    for (int off = 128; off > 0; off >>= 1) {
      if (tid < off) red[tid] = fmaxf(red[tid], red[tid + off]);
      __syncthreads();
    }
    float m = red[0];
    __syncthreads();
    float ls = expf(sc0 - m) + expf(sc1 - m) + (has2 ? expf(sc2 - m) : 0.f);
    red[tid] = ls;
    __syncthreads();
    for (int off = 128; off > 0; off >>= 1) {
      if (tid < off) red[tid] += red[tid + off];
      __syncthreads();
    }
    if (tid == 0) { P.stats[bb * 2] = m; P.stats[bb * 2 + 1] = red[0]; }
  }
}

// ctx for step att_i + att_seq[.][att_i] writes. grid 256.
__global__ __launch_bounds__(256) void k_dec_ctx(DecP P, int att_i) {
  __shared__ float sm[896];
  const int tid = threadIdx.x, bid = blockIdx.x;
  int bb = bid >> 3, wblk = bid & 7;
  float M = P.stats[bb * 2], L = P.stats[bb * 2 + 1];
  float invL = 1.0f / L;
  float* pl = sm;
  for (int t = tid; t < 600; t += 256) {
    float pv = expf(P.scores[bb * 600 + t] - M) * invL;
    pl[t] = pv;
    if (wblk == 0) P.out[15728640ull + (size_t)bb * 72000 + (size_t)att_i * 600 + t] = pv;
  }
  __syncthreads();
  int w = (wblk << 7) + (tid & 127);
  int th = tid >> 7;
  const float* vb = P.val + (size_t)bb * 614400 + w;
  float acc = 0.f;
  #pragma unroll 4
  for (int t = th * 300; t < th * 300 + 300; t++) acc += pl[t] * vb[(size_t)t * 1024];
  float* red = sm + 640;
  red[tid] = acc;
  __syncthreads();
  if (tid < 128) P.ctx[bb * 1024 + (wblk << 7) + tid] = red[tid] + red[tid + 128];
}

// ---------------- launch ----------------
extern "C" void kernel_launch(void* const* d_in, const int* in_sizes, int n_in,
                              void* d_out, int out_size, void* d_ws, size_t ws_size,
                              hipStream_t stream) {
  const float* audio = (const float*)d_in[0];
  const float* Wih_f = (const float*)d_in[1];
  const float* Whh_f = (const float*)d_in[2];
  const float* b_f   = (const float*)d_in[3];
  const float* Wih_b = (const float*)d_in[4];
  const float* Whh_b = (const float*)d_in[5];
  const float* b_b   = (const float*)d_in[6];
  const float* Wq    = (const float*)d_in[7];
  const float* bq    = (const float*)d_in[8];
  const float* Wk    = (const float*)d_in[9];
  const float* bk    = (const float*)d_in[10];
  const float* Wv    = (const float*)d_in[11];
  const float* bv    = (const float*)d_in[12];
  const float* Wih_d = (const float*)d_in[13];
  const float* Whh_d = (const float*)d_in[14];
  const float* b_d   = (const float*)d_in[15];
  const float* Wc    = (const float*)d_in[16];
  const float* bc    = (const float*)d_in[17];
  const float* E     = (const float*)d_in[18];
  const int*   flen  = (const int*)d_in[19];
  float* out = (float*)d_out;
  char* ws = (char*)d_ws;

  float* h_enc   = (float*)(ws + OFF_HENC);
  float* c_enc   = (float*)(ws + OFF_CENC);
  float* h_d     = (float*)(ws + OFF_HD);
  float* c_d     = (float*)(ws + OFF_CD);
  float* last    = (float*)(ws + OFF_LAST);
  float* qbuf    = (float*)(ws + OFF_Q);
  float* ctx     = (float*)(ws + OFF_CTX);
  float* scores  = (float*)(ws + OFF_SCORES);
  float* stats   = (float*)(ws + OFF_STATS);
  float* audio_T = (float*)(ws + OFF_AUDIOT);
  float* enc2    = (float*)(ws + OFF_ENC2);
  float* key_T   = (float*)(ws + OFF_KEYT);
  float* val     = (float*)(ws + OFF_VAL);

  hipMemsetAsync(ws, 0, STATE_BYTES, stream);
  k_init_last<<<64, 256, 0, stream>>>(E, last);
  k_prep_audio<<<(T_ * FIN_ * 32 + 255) / 256, 256, 0, stream>>>(audio, audio_T);

  EncP ep{audio_T, Wih_f, Whh_f, b_f, Wih_b, Whh_b, b_b, h_enc, c_enc, enc2};
  for (int s = 0; s < 600; s++)
    k_enc_step<<<512, 256, 0, stream>>>(ep, s);

  KVP kp{enc2, Wk, bk, Wv, bv, key_T, val};
  k_keyval<<<1800, 256, 0, stream>>>(kp);

  DecP dp{Wq, bq, Wih_d, Whh_d, b_d, Wc, bc, E, flen, key_T, val,
          h_d, c_d, last, qbuf, ctx, scores, stats, out};

  k_dec_logits_q<<<256, 256, 0, stream>>>(dp, -1);  // q_0
  k_dec_amax<<<64, 256, 0, stream>>>(dp, -1, 1);    // scores_0
  k_dec_ctx<<<256, 256, 0, stream>>>(dp, 0);        // ctx_0, att_seq[:,0,:]
  for (int i = 0; i < 120; i++) {
    k_dec_gates<<<256, 256, 0, stream>>>(dp, i);
    k_dec_logits_q<<<256, 256, 0, stream>>>(dp, i);
    k_dec_amax<<<64, 256, 0, stream>>>(dp, i, (i < 119) ? 1 : 0);
    if (i < 119) k_dec_ctx<<<256, 256, 0, stream>>>(dp, i + 1);
  }
}